// Round 3
// baseline (29.267 us; speedup 1.0000x reference)
//
#include <hip/hip_runtime.h>
#include <math.h>

// Problem constants (match reference)
constexpr int B_ = 32, Q_ = 500, N_ = 200, K_ = 16, C_ = 92;
constexpr int TWO_K = 2 * K_;          // 32
constexpr int WAVES = 8;               // waves per block = q's per block
constexpr int THREADS = 64 * WAVES;    // 512
constexpr int TPAD = 34;               // padded LDS row stride (floats) for targets
constexpr float EPS_ = 1e-6f;
constexpr float POLY_SCALE = 5.0f / 32.0f;   // POLY_COST / (2K)

__device__ __forceinline__ float rfl(float v) {
    return __int_as_float(__builtin_amdgcn_readfirstlane(__float_as_int(v)));
}

__global__ __launch_bounds__(THREADS, 8)   // force VGPR <= 64 -> 8 waves/SIMD
void matcher_cost_kernel(const float* __restrict__ logits,   // (B,Q,C)
                         const float* __restrict__ ppoly,    // (B,Q,K,2)
                         const int*   __restrict__ labels,   // (B,N)
                         const float* __restrict__ tpoly,    // (B,N,K,2)
                         float* __restrict__ out)            // (B,Q,N)
{
    __shared__ float sT[N_ * TPAD];       // target polylines, padded rows (27200 B)
    __shared__ float sTB[N_ * 5];         // bbox(4)+area(1), stride 5     (4000 B)
    __shared__ int   sLbl[N_];            // labels                         (800 B)
    __shared__ float sProb[WAVES * C_];   // per-wave class probs          (2944 B)
    // total ~34.1 KB -> 4 blocks/CU by LDS; with VGPR<=64 -> 32 waves/CU

    const int tid  = threadIdx.x;
    const int b    = blockIdx.y;
    const int q0   = blockIdx.x * WAVES;
    const int w    = tid >> 6;            // wave id = local q
    const int lane = tid & 63;
    const int q    = q0 + w;

    // ---------------- stage targets to LDS ----------------
    {
        const float* tb_base = tpoly + (size_t)b * (N_ * TWO_K);
        for (int u = tid; u < N_ * TWO_K / 4; u += THREADS) {
            float4 v = reinterpret_cast<const float4*>(tb_base)[u];
            int n = u >> 3;               // u*4 / 32
            int j = (u & 7) * 4;
            float* d = &sT[n * TPAD + j];
            reinterpret_cast<float2*>(d)[0] = make_float2(v.x, v.y);
            reinterpret_cast<float2*>(d)[1] = make_float2(v.z, v.w);
        }
        for (int n = tid; n < N_; n += THREADS) sLbl[n] = labels[b * N_ + n];
    }
    __syncthreads();

    // ---------------- target bboxes + area ----------------
    for (int n = tid; n < N_; n += THREADS) {
        const float2* tr = reinterpret_cast<const float2*>(&sT[n * TPAD]);
        float xm = INFINITY, ym = INFINITY, xM = -INFINITY, yM = -INFINITY;
        #pragma unroll
        for (int k = 0; k < K_; ++k) {
            float2 t = tr[k];
            xm = fminf(xm, t.x); xM = fmaxf(xM, t.x);
            ym = fminf(ym, t.y); yM = fmaxf(yM, t.y);
        }
        sTB[n * 5 + 0] = xm; sTB[n * 5 + 1] = ym;
        sTB[n * 5 + 2] = xM; sTB[n * 5 + 3] = yM;
        sTB[n * 5 + 4] = (xM - xm) * (yM - ym);
    }
    __syncthreads();

    if (q >= Q_) return;   // tail waves done (no barriers below)

    // ---------------- pred polyline -> SGPRs (wave-uniform q) ----------------
    const int wq = __builtin_amdgcn_readfirstlane(q);
    const float* pp = ppoly + ((size_t)(b * Q_ + wq)) * TWO_K;
    float pfs[TWO_K];
    #pragma unroll
    for (int j = 0; j < TWO_K; ++j) pfs[j] = rfl(pp[j]);   // SGPR-resident

    // pred bbox via 16-lane shuffle reduce (then scalarize)
    float pxm, pym, pxM, pyM;
    {
        float2 p = reinterpret_cast<const float2*>(pp)[lane & 15];
        float xm = p.x, xM = p.x, ym = p.y, yM = p.y;
        #pragma unroll
        for (int off = 8; off; off >>= 1) {
            xm = fminf(xm, __shfl_xor(xm, off));
            xM = fmaxf(xM, __shfl_xor(xM, off));
            ym = fminf(ym, __shfl_xor(ym, off));
            yM = fmaxf(yM, __shfl_xor(yM, off));
        }
        pxm = rfl(xm); pxM = rfl(xM); pym = rfl(ym); pyM = rfl(yM);
    }
    const float parea = (pxM - pxm) * (pyM - pym);

    // ---------------- softmax over 92 classes (64-lane wave) ----------------
    {
        const float* lg = logits + ((size_t)(b * Q_ + wq)) * C_;
        float lv0 = lg[lane];
        float lv1 = (lane < C_ - 64) ? lg[64 + lane] : -INFINITY;
        float m = fmaxf(lv0, lv1);
        #pragma unroll
        for (int off = 32; off; off >>= 1) m = fmaxf(m, __shfl_xor(m, off));
        float e0 = __expf(lv0 - m);
        float e1 = (lane < C_ - 64) ? __expf(lv1 - m) : 0.0f;
        float s = e0 + e1;
        #pragma unroll
        for (int off = 32; off; off >>= 1) s += __shfl_xor(s, off);
        float rs = 1.0f / s;
        sProb[w * C_ + lane] = e0 * rs;
        if (lane < C_ - 64) sProb[w * C_ + 64 + lane] = e1 * rs;
        // same-wave write->read below; compiler orders via lgkmcnt
    }

    float* outRow = out + ((size_t)(b * Q_ + wq)) * N_;
    const float* probRow = &sProb[w * C_];

    // ---------------- main loop: 64 n per iteration ----------------
    for (int i = 0; i < (N_ + 63) / 64; ++i) {
        int n = lane + 64 * i;
        if (n >= N_) break;
        const float2* tr = reinterpret_cast<const float2*>(&sT[n * TPAD]);
        float f0 = 0.0f, f1 = 0.0f, r0 = 0.0f, r1 = 0.0f;   // 4 indep chains
        #pragma unroll
        for (int k = 0; k < K_; ++k) {
            float2 t = tr[k];
            float a = fabsf(pfs[2 * k]     - t.x) + fabsf(pfs[2 * k + 1] - t.y);
            float c = fabsf(pfs[30 - 2 * k] - t.x) + fabsf(pfs[31 - 2 * k] - t.y);
            if (k & 1) { f1 += a; r1 += c; } else { f0 += a; r0 += c; }
        }
        float cpoly = fminf(f0 + f1, r0 + r1) * POLY_SCALE;

        float cclass = -probRow[sLbl[n]];

        float tx0 = sTB[n * 5 + 0], ty0 = sTB[n * 5 + 1];
        float tx1 = sTB[n * 5 + 2], ty1 = sTB[n * 5 + 3];
        float tarea = sTB[n * 5 + 4];
        float ix0 = fmaxf(pxm, tx0), iy0 = fmaxf(pym, ty0);
        float ix1 = fminf(pxM, tx1), iy1 = fminf(pyM, ty1);
        float iw = fmaxf(ix1 - ix0, 0.0f), ih = fmaxf(iy1 - iy0, 0.0f);
        float inter = iw * ih;
        float uni = parea + tarea - inter;
        float iou = inter / fmaxf(uni, EPS_);
        float cx0 = fminf(pxm, tx0), cy0 = fminf(pym, ty0);
        float cx1 = fmaxf(pxM, tx1), cy1 = fmaxf(pyM, ty1);
        float ca = (cx1 - cx0) * (cy1 - cy0);   // cx1>=cx0 by construction
        float giou = iou - (ca - uni) / fmaxf(ca, EPS_);

        outRow[n] = cclass + cpoly - giou;
    }
}

extern "C" void kernel_launch(void* const* d_in, const int* in_sizes, int n_in,
                              void* d_out, int out_size, void* d_ws, size_t ws_size,
                              hipStream_t stream) {
    const float* logits = (const float*)d_in[0];   // (B,Q,C)
    const float* ppoly  = (const float*)d_in[1];   // (B,Q,K,2)
    const int*   labels = (const int*)d_in[2];     // (B,N)
    const float* tpoly  = (const float*)d_in[3];   // (B,N,K,2)
    float* out = (float*)d_out;                    // (B,Q,N)

    dim3 grid((Q_ + WAVES - 1) / WAVES, B_);       // (63, 32)
    matcher_cost_kernel<<<grid, THREADS, 0, stream>>>(logits, ppoly, labels, tpoly, out);
}